// Round 1
// baseline (9.450 us; speedup 1.0000x reference)
//
#include <hip/hip_runtime.h>
#include <hip/hip_bf16.h>

// Closed form of the reference circuit:
//   out[b][i] = prod_{j<=i} cos(pi * x[b][j])
// Derivation: RZ layer is diagonal phase -> no effect on |amp|^2 / <Z>.
// RY layer gives independent bits with E[(-1)^b_j] = cos(pi x_j).
// CNOT chain makes output bit i the prefix parity b_0^...^b_i, whose
// expectation factorizes into the prefix product of cos(pi x_j).

#define N_QUBITS 16
#define BATCH 512

__global__ __launch_bounds__(256) void QuantumLayer_60988535603889_kernel(
    const float* __restrict__ x, float* __restrict__ out) {
    int b = blockIdx.x * blockDim.x + threadIdx.x;
    if (b >= BATCH) return;

    const float4* __restrict__ xin = reinterpret_cast<const float4*>(x + b * N_QUBITS);
    float4 v0 = xin[0];
    float4 v1 = xin[1];
    float4 v2 = xin[2];
    float4 v3 = xin[3];

    float xs[N_QUBITS] = {v0.x, v0.y, v0.z, v0.w,
                          v1.x, v1.y, v1.z, v1.w,
                          v2.x, v2.y, v2.z, v2.w,
                          v3.x, v3.y, v3.z, v3.w};

    const float PI_F = 3.14159265358979323846f;
    float o[N_QUBITS];
    float p = 1.0f;
#pragma unroll
    for (int i = 0; i < N_QUBITS; ++i) {
        p *= cosf(PI_F * xs[i]);
        o[i] = p;
    }

    float4* __restrict__ op = reinterpret_cast<float4*>(out + b * N_QUBITS);
    op[0] = make_float4(o[0], o[1], o[2], o[3]);
    op[1] = make_float4(o[4], o[5], o[6], o[7]);
    op[2] = make_float4(o[8], o[9], o[10], o[11]);
    op[3] = make_float4(o[12], o[13], o[14], o[15]);
}

extern "C" void kernel_launch(void* const* d_in, const int* in_sizes, int n_in,
                              void* d_out, int out_size, void* d_ws, size_t ws_size,
                              hipStream_t stream) {
    const float* x = (const float*)d_in[0];
    float* out = (float*)d_out;
    dim3 grid((BATCH + 255) / 256);
    dim3 block(256);
    QuantumLayer_60988535603889_kernel<<<grid, block, 0, stream>>>(x, out);
}